// Round 4
// baseline (338.999 us; speedup 1.0000x reference)
//
#include <hip/hip_runtime.h>
#include <hip/hip_bf16.h>

typedef __attribute__((ext_vector_type(8))) short sh8;
typedef __attribute__((ext_vector_type(4))) short sh4;
typedef __attribute__((ext_vector_type(4))) float f4v;
typedef __attribute__((ext_vector_type(4))) unsigned u4v;

#define SCALE_Q 0.1803368801f   // 0.125 * log2(e): folds softmax scale AND exp->exp2

__device__ __forceinline__ short f2bf(float f) {
    unsigned u = __builtin_bit_cast(unsigned, f);
    u += 0x7fffu + ((u >> 16) & 1u);   // RNE
    return (short)(u >> 16);
}

#if __has_builtin(__builtin_amdgcn_cvt_pk_bf16_f32)
__device__ __forceinline__ unsigned pk_bf16(float a, float b) {
    return __builtin_bit_cast(unsigned, __builtin_amdgcn_cvt_pk_bf16_f32(a, b));
}
#else
__device__ __forceinline__ unsigned pk_bf16(float a, float b) {
    return (unsigned)(unsigned short)f2bf(a) | ((unsigned)(unsigned short)f2bf(b) << 16);
}
#endif

#if __has_builtin(__builtin_amdgcn_exp2f)
#define EXP2(x) __builtin_amdgcn_exp2f(x)
#else
#define EXP2(x) exp2f(x)
#endif

__device__ __forceinline__ void glds16(const short* g, short* l) {
    __builtin_amdgcn_global_load_lds(
        (const __attribute__((address_space(1))) void*)g,
        (__attribute__((address_space(3))) void*)l, 16, 0, 0);
}

// ---------------- pack: fp32 -> bf16 conversions + weight fusion ----------------
__global__ __launch_bounds__(256)
void pack_all(const float* __restrict__ x,  const float* __restrict__ Wq,
              const float* __restrict__ Wk, const float* __restrict__ Wv,
              const float* __restrict__ Wo, const float* __restrict__ bq,
              const float* __restrict__ bk, const float* __restrict__ bv,
              short* __restrict__ xb, short* __restrict__ Wqkvb,
              short* __restrict__ Wob, float* __restrict__ bqkv)
{
    const long idx = (long)blockIdx.x * 256 + threadIdx.x;
    if (idx >= 2752896) return;
    const float* src; short* dst; float sc = 1.0f; long off;
    if (idx < 2097152)       { off = idx;           src = x;  dst = xb; }
    else if (idx < 2359296)  { off = idx - 2097152; src = Wq; dst = Wqkvb;           sc = SCALE_Q; }
    else if (idx < 2424832)  { off = idx - 2359296; src = Wk; dst = Wqkvb + 1048576; }
    else if (idx < 2490368)  { off = idx - 2424832; src = Wv; dst = Wqkvb + 1310720; }
    else if (idx < 2752512)  { off = idx - 2490368; src = Wo; dst = Wob; }
    else {
        long j = idx - 2752512;  // 0..383
        const float* bs; float* bd; float s2 = 1.0f;
        if (j < 256)      { bs = bq + j * 4;         bd = bqkv + j * 4;         s2 = SCALE_Q; }
        else if (j < 320) { bs = bk + (j - 256) * 4; bd = bqkv + 1024 + (j - 256) * 4; }
        else              { bs = bv + (j - 320) * 4; bd = bqkv + 1280 + (j - 320) * 4; }
        f4v v = *reinterpret_cast<const f4v*>(bs);
        f4v o = { v[0] * s2, v[1] * s2, v[2] * s2, v[3] * s2 };
        *reinterpret_cast<f4v*>(bd) = o;
        return;
    }
    f4v v = *reinterpret_cast<const f4v*>(src + off * 4);
    sh4 o; o[0] = f2bf(v[0] * sc); o[1] = f2bf(v[1] * sc);
    o[2] = f2bf(v[2] * sc); o[3] = f2bf(v[3] * sc);
    *reinterpret_cast<sh4*>(dst + off * 4) = o;
}

// ---------------- m97-style GEMM: C[M,N] = A[M,K] * B[N,K]^T + bias ----------------
template<bool OUT_BF16>
__global__ __launch_bounds__(256)
void gemm_glds(const short* __restrict__ A, const short* __restrict__ B,
               const float* __restrict__ bias, void* __restrict__ Cv,
               int M, int N, int K)
{
    __shared__ __attribute__((aligned(16))) short As[128 * 32];
    __shared__ __attribute__((aligned(16))) short Bs[128 * 32];

    const int t = threadIdx.x, lane = t & 63, w = t >> 6;
    const int lr = lane & 15, quad = lane >> 4;
    const int m0 = blockIdx.y * 128, n0 = blockIdx.x * 128;
    const int wm = (w >> 1) * 64, wn = (w & 1) * 64;
    const int sr = lane >> 2, sc = lane & 3;

    f4v acc[4][4] = {};

    for (int kb = 0; kb < K; kb += 32) {
#pragma unroll
        for (int p = 0; p < 2; ++p) {
            const int s = 2 * w + p;
            const int r = s * 16 + sr;
            const int g = sc ^ ((r >> 1) & 3);
            glds16(A + (size_t)(m0 + r) * K + kb + g * 8, &As[s * 512]);
            glds16(B + (size_t)(n0 + r) * K + kb + g * 8, &Bs[s * 512]);
        }
        __syncthreads();
        sh8 af[4], bfr[4];
#pragma unroll
        for (int i = 0; i < 4; ++i) {
            const int ra = wm + i * 16 + lr;
            af[i] = *reinterpret_cast<const sh8*>(&As[ra * 32 + ((quad ^ ((ra >> 1) & 3)) << 3)]);
            const int rb = wn + i * 16 + lr;
            bfr[i] = *reinterpret_cast<const sh8*>(&Bs[rb * 32 + ((quad ^ ((rb >> 1) & 3)) << 3)]);
        }
#pragma unroll
        for (int mi = 0; mi < 4; ++mi)
#pragma unroll
            for (int ni = 0; ni < 4; ++ni)
                acc[mi][ni] = __builtin_amdgcn_mfma_f32_16x16x32_bf16(af[mi], bfr[ni], acc[mi][ni], 0, 0, 0);
        __syncthreads();
    }

#pragma unroll
    for (int ni = 0; ni < 4; ++ni) {
        const int col = n0 + wn + ni * 16 + lr;
        const float bv = bias[col];
#pragma unroll
        for (int mi = 0; mi < 4; ++mi) {
            const int row = m0 + wm + mi * 16 + quad * 4;
#pragma unroll
            for (int i = 0; i < 4; ++i) {
                float v = acc[mi][ni][i] + bv;
                if constexpr (OUT_BF16)
                    ((short*)Cv)[(size_t)(row + i) * N + col] = f2bf(v);
                else
                    ((float*)Cv)[(size_t)(row + i) * N + col] = v;
            }
        }
    }
}

// ---------------- flash attention: 40KB LDS -> 4 blocks/CU, zero-tail grid ----------------
// QKV fused [8192][1536] bf16: Q 0..1023 (pre-scaled by 0.125*log2e), K 1024..1279,
// V 1280..1535. Key permutation (as R3): P row-write is one b128.
// LDS: Ps[128][128] 32KB (Ks[128][64] aliased in first 16KB) + Vs[32][128] 8KB = 40960B.
// V is staged & PV-MFMA'd in two d-halves. All arrays unpadded, XOR-swizzled on
// 16B chunks: chunk' = chunk ^ (row & 15)  (Ks keeps its own 8-chunk swizzle).
__global__ __launch_bounds__(256, 4)
void flash_attn(const short* __restrict__ QKV, short* __restrict__ Og)
{
    constexpr int L = 2048, LQ = 1536, HD = 64;
    __shared__ __attribute__((aligned(16))) short smem[128 * 128 + 32 * 128]; // 40960 B
    short* Ks = smem;               // [128][64] XOR-swizzled (aliases Ps rows 0..63)
    short* Ps = smem;               // [128][128] swizzled
    short* Vs = smem + 128 * 128;   // [32][128] swizzled (V^T half-d: [d][key])

    const int t = threadIdx.x, lane = t & 63, w = t >> 6;
    const int lr = lane & 15, quad = lane >> 4;
    const int qt = blockIdx.x, h = blockIdx.y, b = blockIdx.z;
    const int kh = h >> 2;
    const int q0 = qt * 128;
    const int kcol = 1024 + kh * HD, vcol = 1280 + kh * HD;

    sh8 qf[2][2];
#pragma unroll
    for (int mi = 0; mi < 2; ++mi)
#pragma unroll
        for (int ks = 0; ks < 2; ++ks)
            qf[mi][ks] = *reinterpret_cast<const sh8*>(
                QKV + (size_t)(b * L + q0 + w * 32 + mi * 16 + lr) * LQ + h * HD + ks * 32 + quad * 8);

    float l_st[2][4] = {};
    f4v o_acc[2][4] = {};

    const int ksr = lane >> 3, ksc = lane & 7;   // K staging: row-in-seg, chunk
    const int vch = lane >> 2, vof = 2 * (lane & 3);  // V write: chunk, offset-in-chunk

    for (int kt = 0; kt < L / 128; ++kt) {
        __syncthreads();                          // A: prev PV/Ps readers done before K restage
        const int kv0 = b * L + kt * 128;
        // stage K permuted via glds: LDS seg s rows s*8+ksr hold key (s&1)*64+ksr*8+(s>>1)
#pragma unroll
        for (int p = 0; p < 4; ++p) {
            const int s = 4 * w + p;
            const int key = (s & 1) * 64 + ksr * 8 + (s >> 1);
            const int g = ksc ^ ksr;
            glds16(QKV + (size_t)(kv0 + key) * LQ + kcol + g * 8, &Ks[s * 512]);
        }
        __syncthreads();                          // B: Ks ready

        // S = Q K^T (permuted keys)
        f4v sa[2][8] = {};
#pragma unroll
        for (int ni = 0; ni < 8; ++ni) {
            const int krow = ni * 16 + lr;
            const int f = krow & 7;
            sh8 kf0 = *reinterpret_cast<const sh8*>(&Ks[krow * 64 + ((quad ^ f) << 3)]);
            sh8 kf1 = *reinterpret_cast<const sh8*>(&Ks[krow * 64 + (((4 + quad) ^ f) << 3)]);
#pragma unroll
            for (int mi = 0; mi < 2; ++mi) {
                sa[mi][ni] = __builtin_amdgcn_mfma_f32_16x16x32_bf16(qf[mi][0], kf0, sa[mi][ni], 0, 0, 0);
                sa[mi][ni] = __builtin_amdgcn_mfma_f32_16x16x32_bf16(qf[mi][1], kf1, sa[mi][ni], 0, 0, 0);
            }
        }
        __syncthreads();                          // C: Ks dead; Ps/V-half0 may be written

        // softmax (exp2, no max) + P row-writes (keys lr*8..lr*8+7 contiguous)
#pragma unroll
        for (int mi = 0; mi < 2; ++mi) {
#pragma unroll
            for (int i = 0; i < 4; ++i) {
                float pv[8]; float lsum = 0.f;
#pragma unroll
                for (int ni = 0; ni < 8; ++ni) {
                    pv[ni] = EXP2(sa[mi][ni][i]);
                    lsum += pv[ni];
                }
                l_st[mi][i] += lsum;
                u4v pk = { pk_bf16(pv[0], pv[1]), pk_bf16(pv[2], pv[3]),
                           pk_bf16(pv[4], pv[5]), pk_bf16(pv[6], pv[7]) };
                const int prow = w * 32 + mi * 16 + quad * 4 + i;
                *reinterpret_cast<u4v*>(&Ps[prow * 128 + ((lr ^ (prow & 15)) << 3)]) = pk;
            }
        }

        // two d-halves: stage V^T half, barrier, PV-MFMA half
#pragma unroll
        for (int hh = 0; hh < 2; ++hh) {
            // stage V^T: wave w covers local d-rows w*8..w*8+7; lane handles keys 2*lane,2*lane+1
            {
                const short* vb = QKV + (size_t)(kv0 + 2 * lane) * LQ + vcol + hh * 32 + w * 8;
                sh8 a  = *reinterpret_cast<const sh8*>(vb);
                sh8 bb = *reinterpret_cast<const sh8*>(vb + LQ);
                u4v au = __builtin_bit_cast(u4v, a), bu = __builtin_bit_cast(u4v, bb);
#pragma unroll
                for (int j2 = 0; j2 < 4; ++j2) {
                    unsigned lo = __builtin_amdgcn_perm(bu[j2], au[j2], 0x05040100u);
                    unsigned hi = __builtin_amdgcn_perm(bu[j2], au[j2], 0x07060302u);
                    const int r0 = w * 8 + 2 * j2, r1 = r0 + 1;
                    *reinterpret_cast<unsigned*>(&Vs[r0 * 128 + ((vch ^ (r0 & 15)) << 3) + vof]) = lo;
                    *reinterpret_cast<unsigned*>(&Vs[r1 * 128 + ((vch ^ (r1 & 15)) << 3) + vof]) = hi;
                }
            }
            __syncthreads();                      // D/F: Vs half ready

#pragma unroll
            for (int kk = 0; kk < 4; ++kk) {
                sh8 pa[2];
#pragma unroll
                for (int mi = 0; mi < 2; ++mi) {
                    const int prow = w * 32 + mi * 16 + lr;
                    pa[mi] = *reinterpret_cast<const sh8*>(
                        &Ps[prow * 128 + (((kk * 4 + quad) ^ lr) << 3)]);
                }
#pragma unroll
                for (int ndl = 0; ndl < 2; ++ndl) {
                    const int rowv = ndl * 16 + lr;
                    sh8 vf = *reinterpret_cast<const sh8*>(
                        &Vs[rowv * 128 + (((kk * 4 + quad) ^ lr) << 3)]);
                    const int nd = hh * 2 + ndl;
#pragma unroll
                    for (int mi = 0; mi < 2; ++mi)
                        o_acc[mi][nd] = __builtin_amdgcn_mfma_f32_16x16x32_bf16(pa[mi], vf, o_acc[mi][nd], 0, 0, 0);
                }
            }
            if (hh == 0) __syncthreads();         // E: Vs half0 readers done before half1 write
        }
    }

#pragma unroll
    for (int mi = 0; mi < 2; ++mi) {
#pragma unroll
        for (int i = 0; i < 4; ++i) {
            float l = l_st[mi][i];
#pragma unroll
            for (int st = 1; st < 16; st <<= 1) l += __shfl_xor(l, st, 64);
            const float inv = 1.0f / l;
            const size_t obase = ((size_t)b * L + q0 + w * 32 + mi * 16 + quad * 4 + i) * 1024 + h * HD;
#pragma unroll
            for (int nd = 0; nd < 4; ++nd)
                Og[obase + nd * 16 + lr] = f2bf(o_acc[mi][nd][i] * inv);
        }
    }
}

extern "C" void kernel_launch(void* const* d_in, const int* in_sizes, int n_in,
                              void* d_out, int out_size, void* d_ws, size_t ws_size,
                              hipStream_t stream)
{
    (void)in_sizes; (void)n_in; (void)out_size; (void)ws_size;
    const float* x  = (const float*)d_in[0];
    const float* Wq = (const float*)d_in[1];
    const float* bq = (const float*)d_in[2];
    const float* Wk = (const float*)d_in[3];
    const float* bk = (const float*)d_in[4];
    const float* Wv = (const float*)d_in[5];
    const float* bv = (const float*)d_in[6];
    const float* Wo = (const float*)d_in[7];
    const float* bo = (const float*)d_in[8];
    float* out = (float*)d_out;

    char* ws = (char*)d_ws;
    short* xb    = (short*)(ws);                     // 8192x1024 bf16 = 16 MB
    short* Ob    = (short*)(ws);                     // aliases xb (dead after QKV GEMM)
    short* Wqkvb = (short*)(ws + 16777216);          // 1536x1024 bf16 = 3 MB
    short* Wob   = (short*)(ws + 19922944);          // 1024x1024 bf16 = 2 MB
    float* bqkv  = (float*)(ws + 22020096);          // 1536 fp32
    short* QKV   = (short*)d_out;                    // 8192x1536 bf16 = 24 MB scratch

    pack_all<<<10754, 256, 0, stream>>>(x, Wq, Wk, Wv, Wo, bq, bk, bv, xb, Wqkvb, Wob, bqkv);
    gemm_glds<true><<<dim3(12, 64), 256, 0, stream>>>(xb, Wqkvb, bqkv, QKV, 8192, 1536, 1024);
    flash_attn<<<dim3(16, 16, 4), 256, 0, stream>>>(QKV, Ob);
    gemm_glds<false><<<dim3(8, 64), 256, 0, stream>>>(Ob, Wob, bo, out, 8192, 1024, 1024);
}

// Round 5
// 301.533 us; speedup vs baseline: 1.1243x; 1.1243x over previous
//
#include <hip/hip_runtime.h>
#include <hip/hip_bf16.h>

typedef __attribute__((ext_vector_type(8))) short sh8;
typedef __attribute__((ext_vector_type(4))) short sh4;
typedef __attribute__((ext_vector_type(4))) float f4v;
typedef __attribute__((ext_vector_type(4))) unsigned u4v;

#define SCALE_Q 0.1803368801f   // 0.125 * log2(e): folds softmax scale AND exp->exp2

__device__ __forceinline__ short f2bf(float f) {
    unsigned u = __builtin_bit_cast(unsigned, f);
    u += 0x7fffu + ((u >> 16) & 1u);   // RNE
    return (short)(u >> 16);
}

#if __has_builtin(__builtin_amdgcn_cvt_pk_bf16_f32)
__device__ __forceinline__ unsigned pk_bf16(float a, float b) {
    return __builtin_bit_cast(unsigned, __builtin_amdgcn_cvt_pk_bf16_f32(a, b));
}
#else
__device__ __forceinline__ unsigned pk_bf16(float a, float b) {
    return (unsigned)(unsigned short)f2bf(a) | ((unsigned)(unsigned short)f2bf(b) << 16);
}
#endif

#if __has_builtin(__builtin_amdgcn_exp2f)
#define EXP2(x) __builtin_amdgcn_exp2f(x)
#else
#define EXP2(x) exp2f(x)
#endif

__device__ __forceinline__ void glds16(const short* g, short* l) {
    __builtin_amdgcn_global_load_lds(
        (const __attribute__((address_space(1))) void*)g,
        (__attribute__((address_space(3))) void*)l, 16, 0, 0);
}

// ---------------- pack: fp32 -> bf16 conversions + weight fusion ----------------
__global__ __launch_bounds__(256)
void pack_all(const float* __restrict__ x,  const float* __restrict__ Wq,
              const float* __restrict__ Wk, const float* __restrict__ Wv,
              const float* __restrict__ Wo, const float* __restrict__ bq,
              const float* __restrict__ bk, const float* __restrict__ bv,
              short* __restrict__ xb, short* __restrict__ Wqkvb,
              short* __restrict__ Wob, float* __restrict__ bqkv)
{
    const long idx = (long)blockIdx.x * 256 + threadIdx.x;
    if (idx >= 2752896) return;
    const float* src; short* dst; float sc = 1.0f; long off;
    if (idx < 2097152)       { off = idx;           src = x;  dst = xb; }
    else if (idx < 2359296)  { off = idx - 2097152; src = Wq; dst = Wqkvb;           sc = SCALE_Q; }
    else if (idx < 2424832)  { off = idx - 2359296; src = Wk; dst = Wqkvb + 1048576; }
    else if (idx < 2490368)  { off = idx - 2424832; src = Wv; dst = Wqkvb + 1310720; }
    else if (idx < 2752512)  { off = idx - 2490368; src = Wo; dst = Wob; }
    else {
        long j = idx - 2752512;  // 0..383
        const float* bs; float* bd; float s2 = 1.0f;
        if (j < 256)      { bs = bq + j * 4;         bd = bqkv + j * 4;         s2 = SCALE_Q; }
        else if (j < 320) { bs = bk + (j - 256) * 4; bd = bqkv + 1024 + (j - 256) * 4; }
        else              { bs = bv + (j - 320) * 4; bd = bqkv + 1280 + (j - 320) * 4; }
        f4v v = *reinterpret_cast<const f4v*>(bs);
        f4v o = { v[0] * s2, v[1] * s2, v[2] * s2, v[3] * s2 };
        *reinterpret_cast<f4v*>(bd) = o;
        return;
    }
    f4v v = *reinterpret_cast<const f4v*>(src + off * 4);
    sh4 o; o[0] = f2bf(v[0] * sc); o[1] = f2bf(v[1] * sc);
    o[2] = f2bf(v[2] * sc); o[3] = f2bf(v[3] * sc);
    *reinterpret_cast<sh4*>(dst + off * 4) = o;
}

// ---------------- m97-style GEMM: C[M,N] = A[M,K] * B[N,K]^T + bias ----------------
template<bool OUT_BF16>
__global__ __launch_bounds__(256)
void gemm_glds(const short* __restrict__ A, const short* __restrict__ B,
               const float* __restrict__ bias, void* __restrict__ Cv,
               int M, int N, int K)
{
    __shared__ __attribute__((aligned(16))) short As[128 * 32];
    __shared__ __attribute__((aligned(16))) short Bs[128 * 32];

    const int t = threadIdx.x, lane = t & 63, w = t >> 6;
    const int lr = lane & 15, quad = lane >> 4;
    const int m0 = blockIdx.y * 128, n0 = blockIdx.x * 128;
    const int wm = (w >> 1) * 64, wn = (w & 1) * 64;
    const int sr = lane >> 2, sc = lane & 3;

    f4v acc[4][4] = {};

    for (int kb = 0; kb < K; kb += 32) {
#pragma unroll
        for (int p = 0; p < 2; ++p) {
            const int s = 2 * w + p;
            const int r = s * 16 + sr;
            const int g = sc ^ ((r >> 1) & 3);
            glds16(A + (size_t)(m0 + r) * K + kb + g * 8, &As[s * 512]);
            glds16(B + (size_t)(n0 + r) * K + kb + g * 8, &Bs[s * 512]);
        }
        __syncthreads();
        sh8 af[4], bfr[4];
#pragma unroll
        for (int i = 0; i < 4; ++i) {
            const int ra = wm + i * 16 + lr;
            af[i] = *reinterpret_cast<const sh8*>(&As[ra * 32 + ((quad ^ ((ra >> 1) & 3)) << 3)]);
            const int rb = wn + i * 16 + lr;
            bfr[i] = *reinterpret_cast<const sh8*>(&Bs[rb * 32 + ((quad ^ ((rb >> 1) & 3)) << 3)]);
        }
#pragma unroll
        for (int mi = 0; mi < 4; ++mi)
#pragma unroll
            for (int ni = 0; ni < 4; ++ni)
                acc[mi][ni] = __builtin_amdgcn_mfma_f32_16x16x32_bf16(af[mi], bfr[ni], acc[mi][ni], 0, 0, 0);
        __syncthreads();
    }

#pragma unroll
    for (int ni = 0; ni < 4; ++ni) {
        const int col = n0 + wn + ni * 16 + lr;
        const float bv = bias[col];
#pragma unroll
        for (int mi = 0; mi < 4; ++mi) {
            const int row = m0 + wm + mi * 16 + quad * 4;
#pragma unroll
            for (int i = 0; i < 4; ++i) {
                float v = acc[mi][ni][i] + bv;
                if constexpr (OUT_BF16)
                    ((short*)Cv)[(size_t)(row + i) * N + col] = f2bf(v);
                else
                    ((float*)Cv)[(size_t)(row + i) * N + col] = v;
            }
        }
    }
}

// ---------------- flash attention: 40KB LDS -> 4 blocks/CU, zero-tail grid ----------------
// QKV fused [8192][1536] bf16: Q 0..1023 (pre-scaled by 0.125*log2e), K 1024..1279,
// V 1280..1535. Key permutation (as R3): P row-write is one b128.
// LDS: Ps[128][128] 32KB (Ks[128][64] aliased in first 16KB) + Vs[32][128] 8KB = 40960B.
// V staged & PV-MFMA'd in two d-halves. All arrays unpadded, XOR-swizzled on 16B
// chunks. NOTE: no min-waves hint — R4's __launch_bounds__(256,4) clamped VGPR to 64
// and spilled sa[2][8] to scratch (WRITE_SIZE 16->239 MB, dur +46 us). LDS caps
// occupancy at 4 blocks/CU on its own.
__global__ __launch_bounds__(256)
void flash_attn(const short* __restrict__ QKV, short* __restrict__ Og)
{
    constexpr int L = 2048, LQ = 1536, HD = 64;
    __shared__ __attribute__((aligned(16))) short smem[128 * 128 + 32 * 128]; // 40960 B
    short* Ks = smem;               // [128][64] XOR-swizzled (aliases Ps rows 0..63)
    short* Ps = smem;               // [128][128] swizzled
    short* Vs = smem + 128 * 128;   // [32][128] swizzled (V^T half-d: [d][key])

    const int t = threadIdx.x, lane = t & 63, w = t >> 6;
    const int lr = lane & 15, quad = lane >> 4;
    const int qt = blockIdx.x, h = blockIdx.y, b = blockIdx.z;
    const int kh = h >> 2;
    const int q0 = qt * 128;
    const int kcol = 1024 + kh * HD, vcol = 1280 + kh * HD;

    sh8 qf[2][2];
#pragma unroll
    for (int mi = 0; mi < 2; ++mi)
#pragma unroll
        for (int ks = 0; ks < 2; ++ks)
            qf[mi][ks] = *reinterpret_cast<const sh8*>(
                QKV + (size_t)(b * L + q0 + w * 32 + mi * 16 + lr) * LQ + h * HD + ks * 32 + quad * 8);

    float l_st[2][4] = {};
    f4v o_acc[2][4] = {};

    const int ksr = lane >> 3, ksc = lane & 7;        // K staging: row-in-seg, chunk
    const int vch = lane >> 2, vof = 2 * (lane & 3);  // V write: chunk, offset-in-chunk

    for (int kt = 0; kt < L / 128; ++kt) {
        __syncthreads();                          // A: prev PV/Ps readers done before K restage
        const int kv0 = b * L + kt * 128;
        // stage K permuted via glds: LDS seg s rows s*8+ksr hold key (s&1)*64+ksr*8+(s>>1)
#pragma unroll
        for (int p = 0; p < 4; ++p) {
            const int s = 4 * w + p;
            const int key = (s & 1) * 64 + ksr * 8 + (s >> 1);
            const int g = ksc ^ ksr;
            glds16(QKV + (size_t)(kv0 + key) * LQ + kcol + g * 8, &Ks[s * 512]);
        }
        __syncthreads();                          // B: Ks ready

        // S = Q K^T (permuted keys)
        f4v sa[2][8] = {};
#pragma unroll
        for (int ni = 0; ni < 8; ++ni) {
            const int krow = ni * 16 + lr;
            const int f = krow & 7;
            sh8 kf0 = *reinterpret_cast<const sh8*>(&Ks[krow * 64 + ((quad ^ f) << 3)]);
            sh8 kf1 = *reinterpret_cast<const sh8*>(&Ks[krow * 64 + (((4 + quad) ^ f) << 3)]);
#pragma unroll
            for (int mi = 0; mi < 2; ++mi) {
                sa[mi][ni] = __builtin_amdgcn_mfma_f32_16x16x32_bf16(qf[mi][0], kf0, sa[mi][ni], 0, 0, 0);
                sa[mi][ni] = __builtin_amdgcn_mfma_f32_16x16x32_bf16(qf[mi][1], kf1, sa[mi][ni], 0, 0, 0);
            }
        }
        __syncthreads();                          // C: Ks dead; Ps/V-half0 may be written

        // softmax (exp2, no max) + P row-writes (keys lr*8..lr*8+7 contiguous)
#pragma unroll
        for (int mi = 0; mi < 2; ++mi) {
#pragma unroll
            for (int i = 0; i < 4; ++i) {
                float pv[8]; float lsum = 0.f;
#pragma unroll
                for (int ni = 0; ni < 8; ++ni) {
                    pv[ni] = EXP2(sa[mi][ni][i]);
                    lsum += pv[ni];
                }
                l_st[mi][i] += lsum;
                u4v pk = { pk_bf16(pv[0], pv[1]), pk_bf16(pv[2], pv[3]),
                           pk_bf16(pv[4], pv[5]), pk_bf16(pv[6], pv[7]) };
                const int prow = w * 32 + mi * 16 + quad * 4 + i;
                *reinterpret_cast<u4v*>(&Ps[prow * 128 + ((lr ^ (prow & 15)) << 3)]) = pk;
            }
        }

        // two d-halves: stage V^T half, barrier, PV-MFMA half
#pragma unroll
        for (int hh = 0; hh < 2; ++hh) {
            {
                const short* vb = QKV + (size_t)(kv0 + 2 * lane) * LQ + vcol + hh * 32 + w * 8;
                sh8 a  = *reinterpret_cast<const sh8*>(vb);
                sh8 bb = *reinterpret_cast<const sh8*>(vb + LQ);
                u4v au = __builtin_bit_cast(u4v, a), bu = __builtin_bit_cast(u4v, bb);
#pragma unroll
                for (int j2 = 0; j2 < 4; ++j2) {
                    unsigned lo = __builtin_amdgcn_perm(bu[j2], au[j2], 0x05040100u);
                    unsigned hi = __builtin_amdgcn_perm(bu[j2], au[j2], 0x07060302u);
                    const int r0 = w * 8 + 2 * j2, r1 = r0 + 1;
                    *reinterpret_cast<unsigned*>(&Vs[r0 * 128 + ((vch ^ (r0 & 15)) << 3) + vof]) = lo;
                    *reinterpret_cast<unsigned*>(&Vs[r1 * 128 + ((vch ^ (r1 & 15)) << 3) + vof]) = hi;
                }
            }
            __syncthreads();                      // D/F: Vs half ready

#pragma unroll
            for (int kk = 0; kk < 4; ++kk) {
                sh8 pa[2];
#pragma unroll
                for (int mi = 0; mi < 2; ++mi) {
                    const int prow = w * 32 + mi * 16 + lr;
                    pa[mi] = *reinterpret_cast<const sh8*>(
                        &Ps[prow * 128 + (((kk * 4 + quad) ^ lr) << 3)]);
                }
#pragma unroll
                for (int ndl = 0; ndl < 2; ++ndl) {
                    const int rowv = ndl * 16 + lr;
                    sh8 vf = *reinterpret_cast<const sh8*>(
                        &Vs[rowv * 128 + (((kk * 4 + quad) ^ lr) << 3)]);
                    const int nd = hh * 2 + ndl;
#pragma unroll
                    for (int mi = 0; mi < 2; ++mi)
                        o_acc[mi][nd] = __builtin_amdgcn_mfma_f32_16x16x32_bf16(pa[mi], vf, o_acc[mi][nd], 0, 0, 0);
                }
            }
            if (hh == 0) __syncthreads();         // E: Vs half0 readers done before half1 write
        }
    }

#pragma unroll
    for (int mi = 0; mi < 2; ++mi) {
#pragma unroll
        for (int i = 0; i < 4; ++i) {
            float l = l_st[mi][i];
#pragma unroll
            for (int st = 1; st < 16; st <<= 1) l += __shfl_xor(l, st, 64);
            const float inv = 1.0f / l;
            const size_t obase = ((size_t)b * L + q0 + w * 32 + mi * 16 + quad * 4 + i) * 1024 + h * HD;
#pragma unroll
            for (int nd = 0; nd < 4; ++nd)
                Og[obase + nd * 16 + lr] = f2bf(o_acc[mi][nd][i] * inv);
        }
    }
}

extern "C" void kernel_launch(void* const* d_in, const int* in_sizes, int n_in,
                              void* d_out, int out_size, void* d_ws, size_t ws_size,
                              hipStream_t stream)
{
    (void)in_sizes; (void)n_in; (void)out_size; (void)ws_size;
    const float* x  = (const float*)d_in[0];
    const float* Wq = (const float*)d_in[1];
    const float* bq = (const float*)d_in[2];
    const float* Wk = (const float*)d_in[3];
    const float* bk = (const float*)d_in[4];
    const float* Wv = (const float*)d_in[5];
    const float* bv = (const float*)d_in[6];
    const float* Wo = (const float*)d_in[7];
    const float* bo = (const float*)d_in[8];
    float* out = (float*)d_out;

    char* ws = (char*)d_ws;
    short* xb    = (short*)(ws);                     // 8192x1024 bf16 = 16 MB
    short* Ob    = (short*)(ws);                     // aliases xb (dead after QKV GEMM)
    short* Wqkvb = (short*)(ws + 16777216);          // 1536x1024 bf16 = 3 MB
    short* Wob   = (short*)(ws + 19922944);          // 1024x1024 bf16 = 2 MB
    float* bqkv  = (float*)(ws + 22020096);          // 1536 fp32
    short* QKV   = (short*)d_out;                    // 8192x1536 bf16 = 24 MB scratch

    pack_all<<<10754, 256, 0, stream>>>(x, Wq, Wk, Wv, Wo, bq, bk, bv, xb, Wqkvb, Wob, bqkv);
    gemm_glds<true><<<dim3(12, 64), 256, 0, stream>>>(xb, Wqkvb, bqkv, QKV, 8192, 1536, 1024);
    flash_attn<<<dim3(16, 16, 4), 256, 0, stream>>>(QKV, Ob);
    gemm_glds<false><<<dim3(8, 64), 256, 0, stream>>>(Ob, Wob, bo, out, 8192, 1024, 1024);
}

// Round 6
// 281.943 us; speedup vs baseline: 1.2024x; 1.0695x over previous
//
#include <hip/hip_runtime.h>
#include <hip/hip_bf16.h>

typedef __attribute__((ext_vector_type(8))) short sh8;
typedef __attribute__((ext_vector_type(4))) short sh4;
typedef __attribute__((ext_vector_type(4))) float f4v;
typedef __attribute__((ext_vector_type(4))) unsigned u4v;
typedef __attribute__((ext_vector_type(2))) unsigned u2v;

#define SCALE_Q 0.1803368801f   // 0.125 * log2(e): folds softmax scale AND exp->exp2

__device__ __forceinline__ short f2bf(float f) {
    unsigned u = __builtin_bit_cast(unsigned, f);
    u += 0x7fffu + ((u >> 16) & 1u);   // RNE
    return (short)(u >> 16);
}

#if __has_builtin(__builtin_amdgcn_cvt_pk_bf16_f32)
__device__ __forceinline__ unsigned pk_bf16(float a, float b) {
    return __builtin_bit_cast(unsigned, __builtin_amdgcn_cvt_pk_bf16_f32(a, b));
}
#else
__device__ __forceinline__ unsigned pk_bf16(float a, float b) {
    return (unsigned)(unsigned short)f2bf(a) | ((unsigned)(unsigned short)f2bf(b) << 16);
}
#endif

#if __has_builtin(__builtin_amdgcn_exp2f)
#define EXP2(x) __builtin_amdgcn_exp2f(x)
#else
#define EXP2(x) exp2f(x)
#endif

__device__ __forceinline__ void glds16(const short* g, short* l) {
    __builtin_amdgcn_global_load_lds(
        (const __attribute__((address_space(1))) void*)g,
        (__attribute__((address_space(3))) void*)l, 16, 0, 0);
}

// ---------------- pack: fp32 -> bf16 conversions + weight fusion ----------------
__global__ __launch_bounds__(256)
void pack_all(const float* __restrict__ x,  const float* __restrict__ Wq,
              const float* __restrict__ Wk, const float* __restrict__ Wv,
              const float* __restrict__ Wo, const float* __restrict__ bq,
              const float* __restrict__ bk, const float* __restrict__ bv,
              short* __restrict__ xb, short* __restrict__ Wqkvb,
              short* __restrict__ Wob, float* __restrict__ bqkv)
{
    const long idx = (long)blockIdx.x * 256 + threadIdx.x;
    if (idx >= 2752896) return;
    const float* src; short* dst; float sc = 1.0f; long off;
    if (idx < 2097152)       { off = idx;           src = x;  dst = xb; }
    else if (idx < 2359296)  { off = idx - 2097152; src = Wq; dst = Wqkvb;           sc = SCALE_Q; }
    else if (idx < 2424832)  { off = idx - 2359296; src = Wk; dst = Wqkvb + 1048576; }
    else if (idx < 2490368)  { off = idx - 2424832; src = Wv; dst = Wqkvb + 1310720; }
    else if (idx < 2752512)  { off = idx - 2490368; src = Wo; dst = Wob; }
    else {
        long j = idx - 2752512;  // 0..383
        const float* bs; float* bd; float s2 = 1.0f;
        if (j < 256)      { bs = bq + j * 4;         bd = bqkv + j * 4;         s2 = SCALE_Q; }
        else if (j < 320) { bs = bk + (j - 256) * 4; bd = bqkv + 1024 + (j - 256) * 4; }
        else              { bs = bv + (j - 320) * 4; bd = bqkv + 1280 + (j - 320) * 4; }
        f4v v = *reinterpret_cast<const f4v*>(bs);
        f4v o = { v[0] * s2, v[1] * s2, v[2] * s2, v[3] * s2 };
        *reinterpret_cast<f4v*>(bd) = o;
        return;
    }
    f4v v = *reinterpret_cast<const f4v*>(src + off * 4);
    sh4 o; o[0] = f2bf(v[0] * sc); o[1] = f2bf(v[1] * sc);
    o[2] = f2bf(v[2] * sc); o[3] = f2bf(v[3] * sc);
    *reinterpret_cast<sh4*>(dst + off * 4) = o;
}

// ---------------- m97-style GEMM: C[M,N] = A[M,K] * W[N,K]^T + bias ----------------
// Blocks with n0 >= n_vstart write their tile TRANSPOSED to Vt[col-n_vstart][row]
// (bf16, token-contiguous) instead of to Cv — produces V^T for the flash kernel.
template<bool OUT_BF16>
__global__ __launch_bounds__(256)
void gemm_glds(const short* __restrict__ A, const short* __restrict__ B,
               const float* __restrict__ bias, void* __restrict__ Cv,
               short* __restrict__ Vt, int n_vstart,
               int M, int N, int K)
{
    __shared__ __attribute__((aligned(16))) short As[128 * 32];
    __shared__ __attribute__((aligned(16))) short Bs[128 * 32];

    const int t = threadIdx.x, lane = t & 63, w = t >> 6;
    const int lr = lane & 15, quad = lane >> 4;
    const int m0 = blockIdx.y * 128, n0 = blockIdx.x * 128;
    const int wm = (w >> 1) * 64, wn = (w & 1) * 64;
    const int sr = lane >> 2, sc = lane & 3;

    f4v acc[4][4] = {};

    for (int kb = 0; kb < K; kb += 32) {
#pragma unroll
        for (int p = 0; p < 2; ++p) {
            const int s = 2 * w + p;
            const int r = s * 16 + sr;
            const int g = sc ^ ((r >> 1) & 3);
            glds16(A + (size_t)(m0 + r) * K + kb + g * 8, &As[s * 512]);
            glds16(B + (size_t)(n0 + r) * K + kb + g * 8, &Bs[s * 512]);
        }
        __syncthreads();
        sh8 af[4], bfr[4];
#pragma unroll
        for (int i = 0; i < 4; ++i) {
            const int ra = wm + i * 16 + lr;
            af[i] = *reinterpret_cast<const sh8*>(&As[ra * 32 + ((quad ^ ((ra >> 1) & 3)) << 3)]);
            const int rb = wn + i * 16 + lr;
            bfr[i] = *reinterpret_cast<const sh8*>(&Bs[rb * 32 + ((quad ^ ((rb >> 1) & 3)) << 3)]);
        }
#pragma unroll
        for (int mi = 0; mi < 4; ++mi)
#pragma unroll
            for (int ni = 0; ni < 4; ++ni)
                acc[mi][ni] = __builtin_amdgcn_mfma_f32_16x16x32_bf16(af[mi], bfr[ni], acc[mi][ni], 0, 0, 0);
        __syncthreads();
    }

    if (OUT_BF16 && n0 >= n_vstart) {
        // V^T epilogue: Vt[d][token], d = col - n_vstart; b64 packed stores
#pragma unroll
        for (int ni = 0; ni < 4; ++ni) {
            const int col = n0 + wn + ni * 16 + lr;
            const float bv = bias[col];
            const size_t d = col - n_vstart;
#pragma unroll
            for (int mi = 0; mi < 4; ++mi) {
                const int row = m0 + wm + mi * 16 + quad * 4;
                u2v pk2 = { pk_bf16(acc[mi][ni][0] + bv, acc[mi][ni][1] + bv),
                            pk_bf16(acc[mi][ni][2] + bv, acc[mi][ni][3] + bv) };
                *reinterpret_cast<u2v*>(&Vt[d * M + row]) = pk2;
            }
        }
        return;
    }

#pragma unroll
    for (int ni = 0; ni < 4; ++ni) {
        const int col = n0 + wn + ni * 16 + lr;
        const float bv = bias[col];
#pragma unroll
        for (int mi = 0; mi < 4; ++mi) {
            const int row = m0 + wm + mi * 16 + quad * 4;
#pragma unroll
            for (int i = 0; i < 4; ++i) {
                float v = acc[mi][ni][i] + bv;
                if constexpr (OUT_BF16)
                    ((short*)Cv)[(size_t)(row + i) * N + col] = f2bf(v);
                else
                    ((float*)Cv)[(size_t)(row + i) * N + col] = v;
            }
        }
    }
}

// ---------------- flash attention: S^T/O^T formulation, P stays in registers ----------------
// Computes S^T = K·Q^T and O^T = V^T·P^T. Ks is staged with a key permutation
// (LDS row r holds key 32*(r>>5) + ((r&15)>>2)*8 + ((r>>4)&1)*4 + (r&3)) chosen so
// the S^T C-layout registers ARE the PV B-operand fragments after exp2+pack —
// no P LDS round-trip, 2 barriers per K-tile. V^T comes pre-transposed from the
// QKV GEMM (Vt[256][8192]) and is staged with glds16. LDS = 16+16 = 32 KB.
// No min-waves launch_bounds (R4: clamping to 64 VGPR spilled 239 MB to scratch).
__global__ __launch_bounds__(256)
void flash_attn(const short* __restrict__ QKV, const short* __restrict__ Vt,
                short* __restrict__ Og)
{
    constexpr int L = 2048, LQ = 1536, HD = 64;
    __shared__ __attribute__((aligned(16))) short smem[128 * 64 + 64 * 128]; // 32768 B
    short* Ks = smem;               // [128 perm-rows][64 d], chunk ^= (r&7)
    short* Vs = smem + 128 * 64;    // [64 d][128 keys],     chunk ^= (r&15)

    const int t = threadIdx.x, lane = t & 63, w = t >> 6;
    const int lr = lane & 15, quad = lane >> 4;
    const int qt = blockIdx.x, h = blockIdx.y, b = blockIdx.z;
    const int kh = h >> 2;
    const int q0 = qt * 128;
    const int kcol = 1024 + kh * HD;

    // Q B-frags (wave owns q-cols w*32..w*32+31 of S^T / O^T)
    sh8 qf[2][2];
#pragma unroll
    for (int nt = 0; nt < 2; ++nt)
#pragma unroll
        for (int ks = 0; ks < 2; ++ks)
            qf[nt][ks] = *reinterpret_cast<const sh8*>(
                QKV + (size_t)(b * L + q0 + w * 32 + nt * 16 + lr) * LQ + h * HD + ks * 32 + quad * 8);

    float l_st[2] = {};
    f4v oT[4][2] = {};

    const int k_r8 = lane >> 3, k_g = lane & 7;   // K staging: row-in-seg, chunk
    const int v_r4 = lane >> 4, v_g = lane & 15;  // V staging: row-in-seg, chunk
    const short* Vbase = Vt + (size_t)kh * HD * 8192;

    for (int kt = 0; kt < L / 128; ++kt) {
        __syncthreads();                          // prev-iter Ks/Vs readers done
        const int kv0 = b * L + kt * 128;
        // stage K permuted: LDS row r holds key kperm(r); swizzle g^=(r&7)
#pragma unroll
        for (int p = 0; p < 4; ++p) {
            const int s = 4 * w + p;
            const int r = s * 8 + k_r8;
            const int mm = r & 15;
            const int key = ((r >> 5) << 5) + ((mm >> 2) << 3) + (((r >> 4) & 1) << 2) + (mm & 3);
            const int g = k_g ^ (r & 7);
            glds16(QKV + (size_t)(kv0 + key) * LQ + kcol + g * 8, &Ks[s * 512]);
        }
        // stage V^T rows (d-major, 256B rows): seg = 4 rows; swizzle g^=(r&15)
#pragma unroll
        for (int p = 0; p < 4; ++p) {
            const int s = 4 * w + p;
            const int r = s * 4 + v_r4;
            const int g = v_g ^ (r & 15);
            glds16(Vbase + (size_t)r * 8192 + kv0 + g * 8, &Vs[s * 512]);
        }
        __syncthreads();                          // tiles ready

#pragma unroll
        for (int half = 0; half < 2; ++half) {
            // S^T for keys [half*64, half*64+64): tiles nl = 0..3
            f4v st[4][2] = {};
#pragma unroll
            for (int nl = 0; nl < 4; ++nl) {
                const int R = (half * 4 + nl) * 16 + lr;
                const int f = lr & 7;
                sh8 a0 = *reinterpret_cast<const sh8*>(&Ks[R * 64 + ((quad ^ f) << 3)]);
                sh8 a1 = *reinterpret_cast<const sh8*>(&Ks[R * 64 + (((4 + quad) ^ f) << 3)]);
#pragma unroll
                for (int nt = 0; nt < 2; ++nt) {
                    st[nl][nt] = __builtin_amdgcn_mfma_f32_16x16x32_bf16(a0, qf[nt][0], st[nl][nt], 0, 0, 0);
                    st[nl][nt] = __builtin_amdgcn_mfma_f32_16x16x32_bf16(a1, qf[nt][1], st[nl][nt], 0, 0, 0);
                }
            }
            // exp2 -> P^T B-frags in registers -> PV MFMA (keys 32c..32c+31 per chunk)
#pragma unroll
            for (int cl = 0; cl < 2; ++cl) {
                const int c = half * 2 + cl;
                sh8 vf[4];
#pragma unroll
                for (int m = 0; m < 4; ++m)
                    vf[m] = *reinterpret_cast<const sh8*>(
                        &Vs[(16 * m + lr) * 128 + (((c * 4 + quad) ^ (lr & 15)) << 3)]);
#pragma unroll
                for (int nt = 0; nt < 2; ++nt) {
                    f4v e0, e1;
#pragma unroll
                    for (int i = 0; i < 4; ++i) {
                        e0[i] = EXP2(st[2 * cl][nt][i]);
                        e1[i] = EXP2(st[2 * cl + 1][nt][i]);
                    }
                    l_st[nt] += (e0[0] + e0[1]) + (e0[2] + e0[3]) +
                                (e1[0] + e1[1]) + (e1[2] + e1[3]);
                    u4v pu = { pk_bf16(e0[0], e0[1]), pk_bf16(e0[2], e0[3]),
                               pk_bf16(e1[0], e1[1]), pk_bf16(e1[2], e1[3]) };
                    sh8 pf = __builtin_bit_cast(sh8, pu);
#pragma unroll
                    for (int m = 0; m < 4; ++m)
                        oT[m][nt] = __builtin_amdgcn_mfma_f32_16x16x32_bf16(vf[m], pf, oT[m][nt], 0, 0, 0);
                }
            }
        }
    }

    // normalize + store O^T -> Og[token][h*64+d]; l reduced across quads (2 shuffles)
#pragma unroll
    for (int nt = 0; nt < 2; ++nt) {
        float l = l_st[nt];
        l += __shfl_xor(l, 16, 64);
        l += __shfl_xor(l, 32, 64);
        const float inv = 1.0f / l;
        const size_t tok = (size_t)b * L + q0 + w * 32 + nt * 16 + lr;
        short* op = Og + tok * 1024 + h * HD + quad * 4;
#pragma unroll
        for (int m = 0; m < 4; ++m) {
            u2v pk2 = { pk_bf16(oT[m][nt][0] * inv, oT[m][nt][1] * inv),
                        pk_bf16(oT[m][nt][2] * inv, oT[m][nt][3] * inv) };
            *reinterpret_cast<u2v*>(op + m * 16) = pk2;
        }
    }
}

extern "C" void kernel_launch(void* const* d_in, const int* in_sizes, int n_in,
                              void* d_out, int out_size, void* d_ws, size_t ws_size,
                              hipStream_t stream)
{
    (void)in_sizes; (void)n_in; (void)out_size; (void)ws_size;
    const float* x  = (const float*)d_in[0];
    const float* Wq = (const float*)d_in[1];
    const float* bq = (const float*)d_in[2];
    const float* Wk = (const float*)d_in[3];
    const float* bk = (const float*)d_in[4];
    const float* Wv = (const float*)d_in[5];
    const float* bv = (const float*)d_in[6];
    const float* Wo = (const float*)d_in[7];
    const float* bo = (const float*)d_in[8];
    float* out = (float*)d_out;

    char* ws = (char*)d_ws;
    short* xb    = (short*)(ws);                     // 8192x1024 bf16 = 16 MB
    short* Ob    = (short*)(ws);                     // aliases xb (dead after QKV GEMM)
    short* Wqkvb = (short*)(ws + 16777216);          // 1536x1024 bf16 = 3 MB
    short* Wob   = (short*)(ws + 19922944);          // 1024x1024 bf16 = 2 MB
    float* bqkv  = (float*)(ws + 22020096);          // 1536 fp32
    short* Vt    = (short*)(ws + 25165824);          // 256x8192 bf16 = 4 MB (V^T)
    short* QKV   = (short*)d_out;                    // 8192x1536 bf16 scratch (V-cols unused)

    pack_all<<<10754, 256, 0, stream>>>(x, Wq, Wk, Wv, Wo, bq, bk, bv, xb, Wqkvb, Wob, bqkv);
    gemm_glds<true><<<dim3(12, 64), 256, 0, stream>>>(xb, Wqkvb, bqkv, QKV, Vt, 1280, 8192, 1536, 1024);
    flash_attn<<<dim3(16, 16, 4), 256, 0, stream>>>(QKV, Vt, Ob);
    gemm_glds<false><<<dim3(8, 64), 256, 0, stream>>>(Ob, Wob, bo, out, nullptr, 1 << 30, 8192, 1024, 1024);
}

// Round 7
// 267.255 us; speedup vs baseline: 1.2684x; 1.0550x over previous
//
#include <hip/hip_runtime.h>
#include <hip/hip_bf16.h>

typedef __attribute__((ext_vector_type(8))) short sh8;
typedef __attribute__((ext_vector_type(4))) short sh4;
typedef __attribute__((ext_vector_type(4))) float f4v;
typedef __attribute__((ext_vector_type(4))) unsigned u4v;
typedef __attribute__((ext_vector_type(2))) unsigned u2v;

#define SCALE_Q 0.1803368801f   // 0.125 * log2(e): folds softmax scale AND exp->exp2

__device__ __forceinline__ short f2bf(float f) {
    unsigned u = __builtin_bit_cast(unsigned, f);
    u += 0x7fffu + ((u >> 16) & 1u);   // RNE
    return (short)(u >> 16);
}

#if __has_builtin(__builtin_amdgcn_cvt_pk_bf16_f32)
__device__ __forceinline__ unsigned pk_bf16(float a, float b) {
    return __builtin_bit_cast(unsigned, __builtin_amdgcn_cvt_pk_bf16_f32(a, b));
}
#else
__device__ __forceinline__ unsigned pk_bf16(float a, float b) {
    return (unsigned)(unsigned short)f2bf(a) | ((unsigned)(unsigned short)f2bf(b) << 16);
}
#endif

#if __has_builtin(__builtin_amdgcn_exp2f)
#define EXP2(x) __builtin_amdgcn_exp2f(x)
#else
#define EXP2(x) exp2f(x)
#endif

__device__ __forceinline__ void glds16(const short* g, short* l) {
    __builtin_amdgcn_global_load_lds(
        (const __attribute__((address_space(1))) void*)g,
        (__attribute__((address_space(3))) void*)l, 16, 0, 0);
}

// ---------------- pack: fp32 -> bf16 conversions + weight fusion ----------------
// vec4 regions: x->xb | Wq->Wqkb(scaled) | Wk->Wqkb+1M | Wv->Wvb | Wo->Wob | biases
__global__ __launch_bounds__(256)
void pack_all(const float* __restrict__ x,  const float* __restrict__ Wq,
              const float* __restrict__ Wk, const float* __restrict__ Wv,
              const float* __restrict__ Wo, const float* __restrict__ bq,
              const float* __restrict__ bk, const float* __restrict__ bv,
              short* __restrict__ xb, short* __restrict__ Wqkb,
              short* __restrict__ Wvb, short* __restrict__ Wob,
              float* __restrict__ bqk, float* __restrict__ bvf)
{
    const long idx = (long)blockIdx.x * 256 + threadIdx.x;
    if (idx >= 2752896) return;
    const float* src; short* dst; float sc = 1.0f; long off;
    if (idx < 2097152)       { off = idx;           src = x;  dst = xb; }
    else if (idx < 2359296)  { off = idx - 2097152; src = Wq; dst = Wqkb;           sc = SCALE_Q; }
    else if (idx < 2424832)  { off = idx - 2359296; src = Wk; dst = Wqkb + 1048576; }
    else if (idx < 2490368)  { off = idx - 2424832; src = Wv; dst = Wvb; }
    else if (idx < 2752512)  { off = idx - 2490368; src = Wo; dst = Wob; }
    else {
        long j = idx - 2752512;  // 0..383
        const float* bs; float* bd; float s2 = 1.0f;
        if (j < 256)      { bs = bq + j * 4;         bd = bqk + j * 4;          s2 = SCALE_Q; }
        else if (j < 320) { bs = bk + (j - 256) * 4; bd = bqk + 1024 + (j - 256) * 4; }
        else              { bs = bv + (j - 320) * 4; bd = bvf + (j - 320) * 4; }
        f4v v = *reinterpret_cast<const f4v*>(bs);
        f4v o = { v[0] * s2, v[1] * s2, v[2] * s2, v[3] * s2 };
        *reinterpret_cast<f4v*>(bd) = o;
        return;
    }
    f4v v = *reinterpret_cast<const f4v*>(src + off * 4);
    sh4 o; o[0] = f2bf(v[0] * sc); o[1] = f2bf(v[1] * sc);
    o[2] = f2bf(v[2] * sc); o[3] = f2bf(v[3] * sc);
    *reinterpret_cast<sh4*>(dst + off * 4) = o;
}

// ---------------- fused projection: QK GEMM + V-transposed GEMM, one grid ----------------
// Blocks 0..639:   QKb[8192][1280] = xb[8192][1024] · Wqkb[1280][1024]^T + bqk (col bias)
// Blocks 640..767: Vt [256][8192]  = Wvb[256][1024] · xb[8192][1024]^T  + bvf (row bias)
//   (swapped operands make the token axis the store-lane axis -> coalesced Vt, no scatter)
// Grid 768 = 3 x 256: zero tail. K=1024, 128x128 tiles, m97-style glds staging.
__global__ __launch_bounds__(256)
void proj_fused(const short* __restrict__ xb, const short* __restrict__ Wqkb,
                const float* __restrict__ bqk, short* __restrict__ QKb,
                const short* __restrict__ Wvb, const float* __restrict__ bvf,
                short* __restrict__ Vt)
{
    constexpr int K = 1024;
    __shared__ __attribute__((aligned(16))) short As[128 * 32];
    __shared__ __attribute__((aligned(16))) short Bs[128 * 32];

    const int t = threadIdx.x, lane = t & 63, w = t >> 6;
    const int lr = lane & 15, quad = lane >> 4;
    const int wm = (w >> 1) * 64, wn = (w & 1) * 64;
    const int sr = lane >> 2, sc = lane & 3;

    const int id = blockIdx.x;
    const short *A, *B; const float* bias; short* C;
    int m0, n0, N; bool brow;
    if (id < 640) {
        A = xb;  B = Wqkb; bias = bqk; C = QKb; N = 1280;
        m0 = (id / 10) * 128; n0 = (id % 10) * 128; brow = false;
    } else {
        const int v = id - 640;
        A = Wvb; B = xb;   bias = bvf; C = Vt;  N = 8192;
        m0 = (v >> 6) * 128; n0 = (v & 63) * 128; brow = true;
    }

    f4v acc[4][4] = {};

    for (int kb = 0; kb < K; kb += 32) {
#pragma unroll
        for (int p = 0; p < 2; ++p) {
            const int s = 2 * w + p;
            const int r = s * 16 + sr;
            const int g = sc ^ ((r >> 1) & 3);
            glds16(A + (size_t)(m0 + r) * K + kb + g * 8, &As[s * 512]);
            glds16(B + (size_t)(n0 + r) * K + kb + g * 8, &Bs[s * 512]);
        }
        __syncthreads();
        sh8 af[4], bfr[4];
#pragma unroll
        for (int i = 0; i < 4; ++i) {
            const int ra = wm + i * 16 + lr;
            af[i] = *reinterpret_cast<const sh8*>(&As[ra * 32 + ((quad ^ ((ra >> 1) & 3)) << 3)]);
            const int rb = wn + i * 16 + lr;
            bfr[i] = *reinterpret_cast<const sh8*>(&Bs[rb * 32 + ((quad ^ ((rb >> 1) & 3)) << 3)]);
        }
#pragma unroll
        for (int mi = 0; mi < 4; ++mi)
#pragma unroll
            for (int ni = 0; ni < 4; ++ni)
                acc[mi][ni] = __builtin_amdgcn_mfma_f32_16x16x32_bf16(af[mi], bfr[ni], acc[mi][ni], 0, 0, 0);
        __syncthreads();
    }

#pragma unroll
    for (int mi = 0; mi < 4; ++mi) {
        const int row = m0 + wm + mi * 16 + quad * 4;
        f4v br4 = {};
        if (brow) br4 = *reinterpret_cast<const f4v*>(&bias[row]);
#pragma unroll
        for (int ni = 0; ni < 4; ++ni) {
            const int col = n0 + wn + ni * 16 + lr;
            const float bc = brow ? 0.f : bias[col];
#pragma unroll
            for (int i = 0; i < 4; ++i) {
                const float v = acc[mi][ni][i] + (brow ? br4[i] : bc);
                C[(size_t)(row + i) * N + col] = f2bf(v);
            }
        }
    }
}

// ---------------- O-projection GEMM: out[M,N] = A[M,K] · W[N,K]^T + bias (fp32 out) ----------------
__global__ __launch_bounds__(256)
void gemm_out(const short* __restrict__ A, const short* __restrict__ B,
              const float* __restrict__ bias, float* __restrict__ Cv,
              int M, int N, int K)
{
    __shared__ __attribute__((aligned(16))) short As[128 * 32];
    __shared__ __attribute__((aligned(16))) short Bs[128 * 32];

    const int t = threadIdx.x, lane = t & 63, w = t >> 6;
    const int lr = lane & 15, quad = lane >> 4;
    const int m0 = blockIdx.y * 128, n0 = blockIdx.x * 128;
    const int wm = (w >> 1) * 64, wn = (w & 1) * 64;
    const int sr = lane >> 2, sc = lane & 3;

    f4v acc[4][4] = {};

    for (int kb = 0; kb < K; kb += 32) {
#pragma unroll
        for (int p = 0; p < 2; ++p) {
            const int s = 2 * w + p;
            const int r = s * 16 + sr;
            const int g = sc ^ ((r >> 1) & 3);
            glds16(A + (size_t)(m0 + r) * K + kb + g * 8, &As[s * 512]);
            glds16(B + (size_t)(n0 + r) * K + kb + g * 8, &Bs[s * 512]);
        }
        __syncthreads();
        sh8 af[4], bfr[4];
#pragma unroll
        for (int i = 0; i < 4; ++i) {
            const int ra = wm + i * 16 + lr;
            af[i] = *reinterpret_cast<const sh8*>(&As[ra * 32 + ((quad ^ ((ra >> 1) & 3)) << 3)]);
            const int rb = wn + i * 16 + lr;
            bfr[i] = *reinterpret_cast<const sh8*>(&Bs[rb * 32 + ((quad ^ ((rb >> 1) & 3)) << 3)]);
        }
#pragma unroll
        for (int mi = 0; mi < 4; ++mi)
#pragma unroll
            for (int ni = 0; ni < 4; ++ni)
                acc[mi][ni] = __builtin_amdgcn_mfma_f32_16x16x32_bf16(af[mi], bfr[ni], acc[mi][ni], 0, 0, 0);
        __syncthreads();
    }

#pragma unroll
    for (int ni = 0; ni < 4; ++ni) {
        const int col = n0 + wn + ni * 16 + lr;
        const float bv = bias[col];
#pragma unroll
        for (int mi = 0; mi < 4; ++mi) {
            const int row = m0 + wm + mi * 16 + quad * 4;
#pragma unroll
            for (int i = 0; i < 4; ++i)
                Cv[(size_t)(row + i) * N + col] = acc[mi][ni][i] + bv;
        }
    }
}

// ---------------- flash attention: S^T/O^T formulation, P stays in registers ----------------
// QKb [8192][1280]: Q cols 0..1023 (pre-scaled by 0.125*log2e), K cols 1024..1279.
// Vt [256][8192]: V^T, token-contiguous rows (from proj_fused's swapped-operand job).
// S^T = K·Q^T with key-permuted Ks staging so S^T C-layout regs ARE PV B-frags after
// exp2+pack — no P LDS round-trip, 2 barriers/K-tile. LDS = 32 KB. No min-waves
// launch_bounds (R4: clamping to 64 VGPR spilled 239 MB to scratch).
__global__ __launch_bounds__(256)
void flash_attn(const short* __restrict__ QKb, const short* __restrict__ Vt,
                short* __restrict__ Og)
{
    constexpr int L = 2048, LQ = 1280, HD = 64;
    __shared__ __attribute__((aligned(16))) short smem[128 * 64 + 64 * 128]; // 32768 B
    short* Ks = smem;               // [128 perm-rows][64 d], chunk ^= (r&7)
    short* Vs = smem + 128 * 64;    // [64 d][128 keys],     chunk ^= (r&15)

    const int t = threadIdx.x, lane = t & 63, w = t >> 6;
    const int lr = lane & 15, quad = lane >> 4;
    const int qt = blockIdx.x, h = blockIdx.y, b = blockIdx.z;
    const int kh = h >> 2;
    const int q0 = qt * 128;
    const int kcol = 1024 + kh * HD;

    // Q B-frags (wave owns q-cols w*32..w*32+31 of S^T / O^T)
    sh8 qf[2][2];
#pragma unroll
    for (int nt = 0; nt < 2; ++nt)
#pragma unroll
        for (int ks = 0; ks < 2; ++ks)
            qf[nt][ks] = *reinterpret_cast<const sh8*>(
                QKb + (size_t)(b * L + q0 + w * 32 + nt * 16 + lr) * LQ + h * HD + ks * 32 + quad * 8);

    float l_st[2] = {};
    f4v oT[4][2] = {};

    const int k_r8 = lane >> 3, k_g = lane & 7;   // K staging: row-in-seg, chunk
    const int v_r4 = lane >> 4, v_g = lane & 15;  // V staging: row-in-seg, chunk
    const short* Vbase = Vt + (size_t)kh * HD * 8192;

    for (int kt = 0; kt < L / 128; ++kt) {
        __syncthreads();                          // prev-iter Ks/Vs readers done
        const int kv0 = b * L + kt * 128;
        // stage K permuted: LDS row r holds key kperm(r); swizzle g^=(r&7)
#pragma unroll
        for (int p = 0; p < 4; ++p) {
            const int s = 4 * w + p;
            const int r = s * 8 + k_r8;
            const int mm = r & 15;
            const int key = ((r >> 5) << 5) + ((mm >> 2) << 3) + (((r >> 4) & 1) << 2) + (mm & 3);
            const int g = k_g ^ (r & 7);
            glds16(QKb + (size_t)(kv0 + key) * LQ + kcol + g * 8, &Ks[s * 512]);
        }
        // stage V^T rows (d-major): seg = 4 rows; swizzle g^=(r&15)
#pragma unroll
        for (int p = 0; p < 4; ++p) {
            const int s = 4 * w + p;
            const int r = s * 4 + v_r4;
            const int g = v_g ^ (r & 15);
            glds16(Vbase + (size_t)r * 8192 + kv0 + g * 8, &Vs[s * 512]);
        }
        __syncthreads();                          // tiles ready

#pragma unroll
        for (int half = 0; half < 2; ++half) {
            // S^T for keys [half*64, half*64+64)
            f4v st[4][2] = {};
#pragma unroll
            for (int nl = 0; nl < 4; ++nl) {
                const int R = (half * 4 + nl) * 16 + lr;
                const int f = lr & 7;
                sh8 a0 = *reinterpret_cast<const sh8*>(&Ks[R * 64 + ((quad ^ f) << 3)]);
                sh8 a1 = *reinterpret_cast<const sh8*>(&Ks[R * 64 + (((4 + quad) ^ f) << 3)]);
#pragma unroll
                for (int nt = 0; nt < 2; ++nt) {
                    st[nl][nt] = __builtin_amdgcn_mfma_f32_16x16x32_bf16(a0, qf[nt][0], st[nl][nt], 0, 0, 0);
                    st[nl][nt] = __builtin_amdgcn_mfma_f32_16x16x32_bf16(a1, qf[nt][1], st[nl][nt], 0, 0, 0);
                }
            }
            // exp2 -> P^T B-frags in registers -> PV MFMA
#pragma unroll
            for (int cl = 0; cl < 2; ++cl) {
                const int c = half * 2 + cl;
                sh8 vf[4];
#pragma unroll
                for (int m = 0; m < 4; ++m)
                    vf[m] = *reinterpret_cast<const sh8*>(
                        &Vs[(16 * m + lr) * 128 + (((c * 4 + quad) ^ (lr & 15)) << 3)]);
#pragma unroll
                for (int nt = 0; nt < 2; ++nt) {
                    f4v e0, e1;
#pragma unroll
                    for (int i = 0; i < 4; ++i) {
                        e0[i] = EXP2(st[2 * cl][nt][i]);
                        e1[i] = EXP2(st[2 * cl + 1][nt][i]);
                    }
                    l_st[nt] += (e0[0] + e0[1]) + (e0[2] + e0[3]) +
                                (e1[0] + e1[1]) + (e1[2] + e1[3]);
                    u4v pu = { pk_bf16(e0[0], e0[1]), pk_bf16(e0[2], e0[3]),
                               pk_bf16(e1[0], e1[1]), pk_bf16(e1[2], e1[3]) };
                    sh8 pf = __builtin_bit_cast(sh8, pu);
#pragma unroll
                    for (int m = 0; m < 4; ++m)
                        oT[m][nt] = __builtin_amdgcn_mfma_f32_16x16x32_bf16(vf[m], pf, oT[m][nt], 0, 0, 0);
                }
            }
        }
    }

    // normalize + store O^T -> Og[token][h*64+d]
#pragma unroll
    for (int nt = 0; nt < 2; ++nt) {
        float l = l_st[nt];
        l += __shfl_xor(l, 16, 64);
        l += __shfl_xor(l, 32, 64);
        const float inv = 1.0f / l;
        const size_t tok = (size_t)b * L + q0 + w * 32 + nt * 16 + lr;
        short* op = Og + tok * 1024 + h * HD + quad * 4;
#pragma unroll
        for (int m = 0; m < 4; ++m) {
            u2v pk2 = { pk_bf16(oT[m][nt][0] * inv, oT[m][nt][1] * inv),
                        pk_bf16(oT[m][nt][2] * inv, oT[m][nt][3] * inv) };
            *reinterpret_cast<u2v*>(op + m * 16) = pk2;
        }
    }
}

extern "C" void kernel_launch(void* const* d_in, const int* in_sizes, int n_in,
                              void* d_out, int out_size, void* d_ws, size_t ws_size,
                              hipStream_t stream)
{
    (void)in_sizes; (void)n_in; (void)out_size; (void)ws_size;
    const float* x  = (const float*)d_in[0];
    const float* Wq = (const float*)d_in[1];
    const float* bq = (const float*)d_in[2];
    const float* Wk = (const float*)d_in[3];
    const float* bk = (const float*)d_in[4];
    const float* Wv = (const float*)d_in[5];
    const float* bv = (const float*)d_in[6];
    const float* Wo = (const float*)d_in[7];
    const float* bo = (const float*)d_in[8];
    float* out = (float*)d_out;

    char* ws = (char*)d_ws;
    short* xb   = (short*)(ws);                     // 8192x1024 bf16 = 16 MB
    short* Ob   = (short*)(ws);                     // aliases xb (dead after proj)
    short* Wqkb = (short*)(ws + 16777216);          // 1280x1024 bf16 = 2.5 MB
    short* Wvb  = (short*)(ws + 19398656);          // 256x1024 bf16 = 512 KB
    short* Wob  = (short*)(ws + 19922944);          // 1024x1024 bf16 = 2 MB
    float* bqk  = (float*)(ws + 22020096);          // 1280 fp32
    float* bvf  = (float*)(ws + 22025216);          // 256 fp32
    short* Vt   = (short*)(ws + 25165824);          // 256x8192 bf16 = 4 MB (V^T)
    short* QKb  = (short*)d_out;                    // 8192x1280 bf16 = 20 MB scratch

    pack_all<<<10754, 256, 0, stream>>>(x, Wq, Wk, Wv, Wo, bq, bk, bv,
                                        xb, Wqkb, Wvb, Wob, bqk, bvf);
    proj_fused<<<768, 256, 0, stream>>>(xb, Wqkb, bqk, QKb, Wvb, bvf, Vt);
    flash_attn<<<dim3(16, 16, 4), 256, 0, stream>>>(QKb, Vt, Ob);
    gemm_out<<<dim3(8, 64), 256, 0, stream>>>(Ob, Wob, bo, out, 8192, 1024, 1024);
}